// Round 16
// baseline (182.255 us; speedup 1.0000x reference)
//
#include <hip/hip_runtime.h>
#include <hip/hip_bf16.h>

// Sizes
#define HXN 10
#define HZN 10
#define BN  256
#define AN  20
#define WUN 128
#define NTILES 6400   // (HXN*HZN) * (BN/4)
#define MROWS 80      // 4 b's * 20 a's per tile

typedef float  f32x4  __attribute__((ext_vector_type(4)));
typedef __bf16 bf16x8 __attribute__((ext_vector_type(8)));
typedef __bf16 bf16x4 __attribute__((ext_vector_type(4)));
typedef unsigned short us8 __attribute__((ext_vector_type(8)));
typedef unsigned short us4 __attribute__((ext_vector_type(4)));
typedef unsigned u32x2 __attribute__((ext_vector_type(2)));

__device__ __forceinline__ unsigned short f2bf(float f) {
  unsigned u = __builtin_bit_cast(unsigned, f);
  u += 0x7fffu + ((u >> 16) & 1u);   // round-to-nearest-even
  return (unsigned short)(u >> 16);
}
// packed f32->bf16 via asm (used only in k_xq, measured-good there)
__device__ __forceinline__ unsigned cvt_pk(float lo, float hi) {
  unsigned r;
  asm("v_cvt_pk_bf16_f32 %0, %1, %2" : "=v"(r) : "v"(lo), "v"(hi));
  return r;
}
__device__ __forceinline__ float elu(float x) {
  return x > 0.f ? x : (__expf(x) - 1.f);
}
// column permutation so a lane's 8 fragment elements are contiguous:
// col = kk*32 + kappa(lg,e), kappa = (e<4)? 4lg+e : 16+4lg+(e-4)
// perm(col) = kk*32 + lg*8 + e
__device__ __forceinline__ int permc(int c) {
  return (c >> 5) * 32 + ((c >> 2) & 3) * 8 + ((c >> 4) & 1) * 4 + (c & 3);
}

// ------- merged pre-stage: k_prep (blocks 0..103) + k_zh (104..743) +
//         k_r (744..1383). All three are independent; one launch. ----------
__global__ __launch_bounds__(256) void k_pre(
    const float* __restrict__ X, const float* __restrict__ Z,
    const float* __restrict__ Wx0, const float* __restrict__ WxR,
    const float* __restrict__ Wz0, const float* __restrict__ WzR,
    const float* __restrict__ bz, const float* __restrict__ Wu0,
    const float* __restrict__ bu,
    unsigned short* __restrict__ WxP, unsigned short* __restrict__ WuP,
    float* __restrict__ Pz, float* __restrict__ R)
{
  const int blk = blockIdx.x;
  const int tid = threadIdx.x;

  if (blk < 104) {
    // ---- k_prep: 4 units of 64 threads; unit id u in [0,416) ----
    const int u = blk * 4 + (tid >> 6);
    if (u >= 416) return;
    const int lane = tid & 63;
    const int l16 = lane & 15, lg = lane >> 4;
    us8 o;
    if (u < 400) {
      const int hx = u / 40, rem = u % 40;
      const int l = rem >> 3, rem2 = rem & 7;
      const int kk = rem2 >> 2, mt = rem2 & 3;
      const int m = mt * 16 + l16;
      #pragma unroll
      for (int e = 0; e < 8; ++e) {
        const int k = kk * 32 + ((e < 4) ? (4 * lg + e) : (16 + 4 * lg + (e - 4)));
        float v;
        if (l == 0) v = (k < 40) ? Wx0[hx * 2560 + k * 64 + m] : 0.f;
        else        v = WxR[((l - 1) * 10 + hx) * 4096 + k * 64 + m];
        o[e] = f2bf(v);
      }
      *reinterpret_cast<us8*>(&WxP[(size_t)((((hx * 5 + l) * 2 + kk) * 4 + mt) * 64 + lane) * 8]) = o;
    } else {
      const int i = u - 400;
      const int kk = i >> 3, mt = i & 7;
      #pragma unroll
      for (int e = 0; e < 8; ++e) {
        const int k = kk * 32 + ((e < 4) ? (4 * lg + e) : (16 + 4 * lg + (e - 4)));
        o[e] = f2bf(Wu0[(40 + k) * 128 + mt * 16 + l16]);
      }
      *reinterpret_cast<us8*>(&WuP[((kk * 8 + mt) * 64 + lane) * 8]) = o;
    }
  } else if (blk < 744) {
    // ---- k_zh: 4 (hz,b) units per block, identical barrier path per unit ----
    __shared__ float cur[4][2][64];
    const int g = tid >> 6, j = tid & 63;
    const int unit = (blk - 104) * 4 + g;      // 0..2559
    const int hz = unit >> 8;
    const int b  = unit & 255;
    cur[g][0][j] = Z[b * 64 + j];
    __syncthreads();
    {
      float acc = bz[hz * 64 + j];
      for (int i = 0; i < 64; ++i) acc += cur[g][0][i] * Wz0[hz * 4096 + i * 64 + j];
      cur[g][1][j] = elu(acc);
    }
    __syncthreads();
    for (int m = 1; m < 5; ++m) {
      const int s = m & 1, d = s ^ 1;
      float acc = bz[m * (HZN * 64) + hz * 64 + j];
      const float* W = WzR + ((m - 1) * HZN + hz) * 4096;
      for (int i = 0; i < 64; ++i) acc += cur[g][s][i] * W[i * 64 + j];
      __syncthreads();
      cur[g][d][j] = elu(acc);
      __syncthreads();
    }
    for (int t = 0; t < 2; ++t) {
      const int col = j + t * 64;
      float s2 = 0.f;
      for (int i = 0; i < 64; ++i) s2 += cur[g][1][i] * Wu0[(104 + i) * 128 + col];
      Pz[(hz * BN + b) * 128 + permc(col)] = s2;
    }
  } else {
    // ---- k_r: R = X@Wu0[0:40] + Z@Wu0[168:232] + bu0 ----
    __shared__ float xs[8][40];
    __shared__ float zs[8][64];
    const int r0 = (blk - 744) * 8;
    for (int idx = tid; idx < 320; idx += 256) xs[idx / 40][idx % 40] = X[r0 * 40 + idx];
    for (int idx = tid; idx < 512; idx += 256) {
      const int row = idx >> 6, c = idx & 63;
      zs[row][c] = Z[((r0 + row) / 20) * 64 + c];
    }
    __syncthreads();
    const int row = tid >> 5, cg = tid & 31;
    f32x4 acc = *reinterpret_cast<const f32x4*>(&bu[cg * 4]);
    #pragma unroll 4
    for (int k = 0; k < 40; ++k) {
      const float xv = xs[row][k];
      const f32x4 wv = *reinterpret_cast<const f32x4*>(&Wu0[k * 128 + cg * 4]);
      acc += xv * wv;
    }
    #pragma unroll 4
    for (int k = 0; k < 64; ++k) {
      const float zv = zs[row][k];
      const f32x4 wv = *reinterpret_cast<const f32x4*>(&Wu0[(168 + k) * 128 + cg * 4]);
      acc += zv * wv;
    }
    *reinterpret_cast<f32x4*>(&R[(r0 + row) * 128 + cg * 4]) = acc;
  }
}

// -------- eps(X) nets via MFMA, fused with Q = R + Xh@Wu0[40:104] ------------
// Q written as bf16 (perm cols).
__global__ __launch_bounds__(256) void k_xq(
    const float* __restrict__ X, const float* __restrict__ bx,
    const float* __restrict__ R,
    const unsigned short* __restrict__ WxP, const unsigned short* __restrict__ WuP,
    unsigned short* __restrict__ Qb)
{
  __shared__ __align__(16) unsigned char bufA[10240];  // [kk 2][nt 5][lane 64][16B]
  __shared__ __align__(16) unsigned char bufB[10240];
  const int hx = blockIdx.x >> 6;
  const int rt = blockIdx.x & 63;
  const int r0 = rt * 80;
  const int tid = threadIdx.x;
  const int w = tid >> 6, lane = tid & 63;
  const int l16 = lane & 15, lg = lane >> 4;
  const int lane16 = lane * 16;

  bf16x8 WA[5][2];
  #pragma unroll
  for (int l = 0; l < 5; ++l)
    #pragma unroll
    for (int kk = 0; kk < 2; ++kk)
      WA[l][kk] = *reinterpret_cast<const bf16x8*>(
          &WxP[(size_t)((((hx * 5 + l) * 2 + kk) * 4 + w) * 64 + lane) * 8]);
  bf16x8 WQ[2][2];
  #pragma unroll
  for (int kk = 0; kk < 2; ++kk)
    #pragma unroll
    for (int mt2 = 0; mt2 < 2; ++mt2)
      WQ[kk][mt2] = *reinterpret_cast<const bf16x8*>(
          &WuP[((kk * 8 + 2 * w + mt2) * 64 + lane) * 8]);

  for (int idx = tid; idx < 5120; idx += 256) {
    const int row = idx >> 6, k = idx & 63;
    const float v = (k < 40) ? X[(r0 + row) * 40 + k] : 0.f;
    const int kk = k >> 5, kl = k & 31;
    const int flg = (kl & 15) >> 2, fe = (kl & 3) + 4 * (kl >> 4);
    const int fl = (row & 15) + 16 * flg, nt = row >> 4;
    *reinterpret_cast<unsigned short*>(bufA + ((kk * 5 + nt) * 64 + fl) * 16 + fe * 2) = f2bf(v);
  }
  __syncthreads();

  const int kkp = w >> 1, half = w & 1;
  #pragma unroll
  for (int l = 0; l < 5; ++l) {
    const unsigned char* src = (l & 1) ? bufB : bufA;
    unsigned char* dst = (l & 1) ? bufA : bufB;
    const f32x4 bias = *reinterpret_cast<const f32x4*>(&bx[(l * 10 + hx) * 64 + w * 16 + 4 * lg]);
    #pragma unroll
    for (int nt = 0; nt < 5; ++nt) {
      const bf16x8 B0 = *reinterpret_cast<const bf16x8*>(src + nt * 1024 + lane16);
      const bf16x8 B1 = *reinterpret_cast<const bf16x8*>(src + (5 + nt) * 1024 + lane16);
      f32x4 acc = bias;
      acc = __builtin_amdgcn_mfma_f32_16x16x32_bf16(WA[l][0], B0, acc, 0, 0, 0);
      acc = __builtin_amdgcn_mfma_f32_16x16x32_bf16(WA[l][1], B1, acc, 0, 0, 0);
      u32x2 o;
      o[0] = cvt_pk(elu(acc[0]), elu(acc[1]));
      o[1] = cvt_pk(elu(acc[2]), elu(acc[3]));
      *reinterpret_cast<u32x2*>(dst + (kkp * 5 + nt) * 1024 + lane16 + half * 8) = o;
    }
    __syncthreads();
  }

  #pragma unroll
  for (int nt = 0; nt < 5; ++nt) {
    const bf16x8 B0 = *reinterpret_cast<const bf16x8*>(bufB + nt * 1024 + lane16);
    const bf16x8 B1 = *reinterpret_cast<const bf16x8*>(bufB + (5 + nt) * 1024 + lane16);
    const int grow = r0 + nt * 16 + l16;
    #pragma unroll
    for (int mt2 = 0; mt2 < 2; ++mt2) {
      f32x4 acc = *reinterpret_cast<const f32x4*>(&R[grow * 128 + (2 * w + mt2) * 16 + 4 * lg]);
      acc = __builtin_amdgcn_mfma_f32_16x16x32_bf16(WQ[0][mt2], B0, acc, 0, 0, 0);
      acc = __builtin_amdgcn_mfma_f32_16x16x32_bf16(WQ[1][mt2], B1, acc, 0, 0, 0);
      us4 o;
      #pragma unroll
      for (int r = 0; r < 4; ++r) {
        __bf16 h = (__bf16)acc[r];
        o[r] = __builtin_bit_cast(unsigned short, h);
      }
      *reinterpret_cast<us4*>(&Qb[(size_t)hx * 655360 + grow * 128 + w * 32 + lg * 8 + 4 * mt2]) = o;
    }
  }
}

// ---------------- fused 4x[128x128] MLP + logits + softmax ----------------
// R13/R15 kernel body unchanged (best measured ~137us). Single delta vs R15:
// grid 512 -> 768 (3 blocks/CU). At VGPR=64 / LDS 43.5KB / 512 threads, all
// three residency budgets allow 3 blocks (LDS 130.5<=160KB, 24 waves<=32,
// 384 VGPR<=512/SIMD). 6400=768*8+256 -> per-CU {b,b+256,b+512} = 25 tiles.
__global__ __launch_bounds__(512, 4) void k_fused(
    const unsigned short* __restrict__ Qb, const float* __restrict__ Pz,
    const float* __restrict__ WuR, const float* __restrict__ bu,
    const float* __restrict__ Wlast, float* __restrict__ partial)
{
  __shared__ __align__(16) unsigned char frag[2][20480]; // [kk][nt][lane][16B]
  __shared__ float lgpS[640];                            // [wave 8][80 rows]

  const int tid  = threadIdx.x;
  const int w    = tid >> 6;           // 0..7
  const int lane = tid & 63;
  const int l16  = lane & 15;
  const int lg   = lane >> 4;
  const int lane16 = lane * 16;
  const int kkw  = w >> 1, half = w & 1;

  // ---- per-wave weight A-fragments, cols [16w,16w+16), all 4 layers ----
  bf16x8 wfrag[4][4];
  #pragma unroll
  for (int l = 0; l < 4; ++l)
    #pragma unroll
    for (int kk = 0; kk < 4; ++kk) {
      us8 wv;
      #pragma unroll
      for (int e = 0; e < 8; ++e) {
        const int k = kk * 32 + ((e < 4) ? (4 * lg + e) : (16 + 4 * lg + (e - 4)));
        const int out = w * 16 + l16;
        wv[e] = f2bf(WuR[l * 16384 + k * 128 + out]);
      }
      wfrag[l][kk] = __builtin_bit_cast(bf16x8, wv);
    }

  // Wlast fragment for this wave's 16 cols
  const f32x4 wl0 = *reinterpret_cast<const f32x4*>(&Wlast[w * 16 + 4 * lg]);

  // tile-invariant per-lane offsets (wave stages perm cols kkw*32+lg*8+4*half..+4)
  int qoff[5], pzoff[5];
  #pragma unroll
  for (int nt = 0; nt < 5; ++nt) {
    const int rloc = nt * 16 + l16;
    qoff[nt]  = rloc * 128 + kkw * 32 + lg * 8 + half * 4;        // ushort units
    pzoff[nt] = (rloc / 20) * 128 + kkw * 32 + lg * 8 + half * 4; // float units
  }

  for (int tile = blockIdx.x; tile < NTILES; tile += gridDim.x) {
    const int H  = tile >> 6;
    const int tb = tile & 63;
    const int hx = H / HZN, hz = H % HZN;
    const unsigned short* qp = Qb + (size_t)hx * 655360 + tb * (80 * 128);
    const float* pzt = Pz + (hz * BN + tb * 4) * 128;

    // ---- stage u1 = elu(Q + Pz): wave w fills its half-slice (8B/lane/nt) ----
    #pragma unroll
    for (int nt = 0; nt < 5; ++nt) {
      const bf16x4 q4 = *reinterpret_cast<const bf16x4*>(qp + qoff[nt]);
      const f32x4 pz = *reinterpret_cast<const f32x4*>(pzt + pzoff[nt]);
      bf16x4 o;
      #pragma unroll
      for (int e = 0; e < 4; ++e) o[e] = (__bf16)elu((float)q4[e] + pz[e]);
      *reinterpret_cast<bf16x4*>(frag[0] + (kkw * 5 + nt) * 1024 + lane16 + half * 8) = o;
    }
    __syncthreads();

    // ---- 4 hidden layers ----
    #pragma unroll
    for (int l = 0; l < 4; ++l) {
      const unsigned char* rdb = frag[l & 1];
      unsigned char* wrb = frag[(l & 1) ^ 1];
      const f32x4 bia = *reinterpret_cast<const f32x4*>(&bu[(l + 1) * 128 + w * 16 + 4 * lg]);
      #pragma unroll
      for (int nt = 0; nt < 5; ++nt) {
        f32x4 a0 = bia;
        #pragma unroll
        for (int kk = 0; kk < 4; ++kk) {
          const bf16x8 bfr = *reinterpret_cast<const bf16x8*>(rdb + (kk * 5 + nt) * 1024 + lane16);
          a0 = __builtin_amdgcn_mfma_f32_16x16x32_bf16(wfrag[l][kk], bfr, a0, 0, 0, 0);
        }
        if (l < 3) {
          bf16x4 o;
          #pragma unroll
          for (int r = 0; r < 4; ++r) o[r] = (__bf16)elu(a0[r]);
          *reinterpret_cast<bf16x4*>(wrb + (kkw * 5 + nt) * 1024 + lane16 + half * 8) = o;
        } else {
          float ps = 0.f;
          #pragma unroll
          for (int r = 0; r < 4; ++r) ps += elu(a0[r]) * wl0[r];
          ps += __shfl_xor(ps, 16);
          ps += __shfl_xor(ps, 32);
          if (lane < 16) lgpS[w * 80 + nt * 16 + l16] = ps;
        }
      }
      __syncthreads();
    }

    // ---- softmax: waves 0..3 handle b-group w (20 rows) ----
    if (w < 4) {
      const int a = lane;
      const int ar = (a < 20) ? a : 0;
      const int row = w * 20 + ar;
      float v = 0.f;
      #pragma unroll
      for (int j = 0; j < 8; ++j) v += lgpS[j * 80 + row];
      float m = (a < 20) ? v : -3.4e38f;
      #pragma unroll
      for (int off = 1; off <= 16; off <<= 1) m = fmaxf(m, __shfl_xor(m, off));
      float e = (a < 20) ? __expf(v - m) : 0.f;
      float s = e;
      #pragma unroll
      for (int off = 1; off <= 16; off <<= 1) s += __shfl_xor(s, off);
      float p = e / s;
      p = (p + 1e-6f) * (1.f / (1.f + 20.f * 1e-6f));
      if (a < 20) partial[(size_t)H * 5120 + tb * 80 + row] = p;
    }
    // frag[0] last read at l=2 (2 barriers before next staging); lgpS written
    // at l=3 pre-barrier, read by softmax post-barrier, rewritten 4 barriers
    // later. Safe without an extra barrier (same argument as R9/R12).
  }
}

// ---------------- mean over the 100 (hx,hz) samples ----------------
__global__ void k_reduce(const float* __restrict__ partial, float* __restrict__ out)
{
  const int i = blockIdx.x * 256 + threadIdx.x;
  if (i < 5120) {
    float s = 0.f;
    for (int h = 0; h < 100; ++h) s += partial[(size_t)h * 5120 + i];
    out[i] = s * 0.01f;
  }
}

extern "C" void kernel_launch(void* const* d_in, const int* in_sizes, int n_in,
                              void* d_out, int out_size, void* d_ws, size_t ws_size,
                              hipStream_t stream)
{
  const float* X     = (const float*)d_in[0];
  const float* Z     = (const float*)d_in[1];
  const float* Wx0   = (const float*)d_in[2];
  const float* WxR   = (const float*)d_in[3];
  const float* bx    = (const float*)d_in[4];
  const float* Wz0   = (const float*)d_in[5];
  const float* WzR   = (const float*)d_in[6];
  const float* bz    = (const float*)d_in[7];
  const float* Wu0   = (const float*)d_in[8];
  const float* WuR   = (const float*)d_in[9];
  const float* bu    = (const float*)d_in[10];
  const float* Wlast = (const float*)d_in[11];
  float* out = (float*)d_out;

  float* ws      = (float*)d_ws;
  float* Pz      = ws;                          // 327,680 f32
  float* Rb      = Pz + 327680;                 // 655,360 f32
  unsigned short* Qb = (unsigned short*)(Rb + 655360);  // 6,553,600 us
  float* partial = (float*)(Qb + 6553600);      // 512,000 f32
  unsigned short* WxP = (unsigned short*)(partial + 512000);  // 204,800 us
  unsigned short* WuP = WxP + 204800;           // 8,192 us

  hipLaunchKernelGGL(k_pre, dim3(1384), dim3(256), 0, stream,
                     X, Z, Wx0, WxR, Wz0, WzR, bz, Wu0, bu, WxP, WuP, Pz, Rb);
  hipLaunchKernelGGL(k_xq, dim3(640), dim3(256), 0, stream, X, bx, Rb, WxP, WuP, Qb);
  hipLaunchKernelGGL(k_fused, dim3(768), dim3(512), 0, stream, Qb, Pz, WuR, bu, Wlast, partial);
  hipLaunchKernelGGL(k_reduce, dim3(20), dim3(256), 0, stream, partial, out);
}

// Round 17
// 168.779 us; speedup vs baseline: 1.0798x; 1.0798x over previous
//
#include <hip/hip_runtime.h>
#include <hip/hip_bf16.h>

// Sizes
#define HXN 10
#define HZN 10
#define BN  256
#define AN  20
#define WUN 128
#define NTILES 6400   // (HXN*HZN) * (BN/4)
#define MROWS 80      // 4 b's * 20 a's per tile

typedef float  f32x4  __attribute__((ext_vector_type(4)));
typedef __bf16 bf16x8 __attribute__((ext_vector_type(8)));
typedef __bf16 bf16x4 __attribute__((ext_vector_type(4)));
typedef unsigned short us8 __attribute__((ext_vector_type(8)));
typedef unsigned short us4 __attribute__((ext_vector_type(4)));
typedef unsigned u32x2 __attribute__((ext_vector_type(2)));

__device__ __forceinline__ unsigned short f2bf(float f) {
  unsigned u = __builtin_bit_cast(unsigned, f);
  u += 0x7fffu + ((u >> 16) & 1u);   // round-to-nearest-even
  return (unsigned short)(u >> 16);
}
// packed f32->bf16 via asm (used only in k_xq, measured-good there)
__device__ __forceinline__ unsigned cvt_pk(float lo, float hi) {
  unsigned r;
  asm("v_cvt_pk_bf16_f32 %0, %1, %2" : "=v"(r) : "v"(lo), "v"(hi));
  return r;
}
__device__ __forceinline__ float elu(float x) {
  return x > 0.f ? x : (__expf(x) - 1.f);
}
// column permutation so a lane's 8 fragment elements are contiguous:
// col = kk*32 + kappa(lg,e), kappa = (e<4)? 4lg+e : 16+4lg+(e-4)
// perm(col) = kk*32 + lg*8 + e
__device__ __forceinline__ int permc(int c) {
  return (c >> 5) * 32 + ((c >> 2) & 3) * 8 + ((c >> 4) & 1) * 4 + (c & 3);
}

// ------- merged pre-stage: k_prep (blocks 0..103) + k_zh (104..743) +
//         k_r (744..1383). All three are independent; one launch. ----------
__global__ __launch_bounds__(256) void k_pre(
    const float* __restrict__ X, const float* __restrict__ Z,
    const float* __restrict__ Wx0, const float* __restrict__ WxR,
    const float* __restrict__ Wz0, const float* __restrict__ WzR,
    const float* __restrict__ bz, const float* __restrict__ Wu0,
    const float* __restrict__ bu,
    unsigned short* __restrict__ WxP, unsigned short* __restrict__ WuP,
    float* __restrict__ Pz, float* __restrict__ R)
{
  const int blk = blockIdx.x;
  const int tid = threadIdx.x;

  if (blk < 104) {
    // ---- k_prep: 4 units of 64 threads; unit id u in [0,416) ----
    const int u = blk * 4 + (tid >> 6);
    if (u >= 416) return;
    const int lane = tid & 63;
    const int l16 = lane & 15, lg = lane >> 4;
    us8 o;
    if (u < 400) {
      const int hx = u / 40, rem = u % 40;
      const int l = rem >> 3, rem2 = rem & 7;
      const int kk = rem2 >> 2, mt = rem2 & 3;
      const int m = mt * 16 + l16;
      #pragma unroll
      for (int e = 0; e < 8; ++e) {
        const int k = kk * 32 + ((e < 4) ? (4 * lg + e) : (16 + 4 * lg + (e - 4)));
        float v;
        if (l == 0) v = (k < 40) ? Wx0[hx * 2560 + k * 64 + m] : 0.f;
        else        v = WxR[((l - 1) * 10 + hx) * 4096 + k * 64 + m];
        o[e] = f2bf(v);
      }
      *reinterpret_cast<us8*>(&WxP[(size_t)((((hx * 5 + l) * 2 + kk) * 4 + mt) * 64 + lane) * 8]) = o;
    } else {
      const int i = u - 400;
      const int kk = i >> 3, mt = i & 7;
      #pragma unroll
      for (int e = 0; e < 8; ++e) {
        const int k = kk * 32 + ((e < 4) ? (4 * lg + e) : (16 + 4 * lg + (e - 4)));
        o[e] = f2bf(Wu0[(40 + k) * 128 + mt * 16 + l16]);
      }
      *reinterpret_cast<us8*>(&WuP[((kk * 8 + mt) * 64 + lane) * 8]) = o;
    }
  } else if (blk < 744) {
    // ---- k_zh: 4 (hz,b) units per block, identical barrier path per unit ----
    __shared__ float cur[4][2][64];
    const int g = tid >> 6, j = tid & 63;
    const int unit = (blk - 104) * 4 + g;      // 0..2559
    const int hz = unit >> 8;
    const int b  = unit & 255;
    cur[g][0][j] = Z[b * 64 + j];
    __syncthreads();
    {
      float acc = bz[hz * 64 + j];
      for (int i = 0; i < 64; ++i) acc += cur[g][0][i] * Wz0[hz * 4096 + i * 64 + j];
      cur[g][1][j] = elu(acc);
    }
    __syncthreads();
    for (int m = 1; m < 5; ++m) {
      const int s = m & 1, d = s ^ 1;
      float acc = bz[m * (HZN * 64) + hz * 64 + j];
      const float* W = WzR + ((m - 1) * HZN + hz) * 4096;
      for (int i = 0; i < 64; ++i) acc += cur[g][s][i] * W[i * 64 + j];
      __syncthreads();
      cur[g][d][j] = elu(acc);
      __syncthreads();
    }
    for (int t = 0; t < 2; ++t) {
      const int col = j + t * 64;
      float s2 = 0.f;
      for (int i = 0; i < 64; ++i) s2 += cur[g][1][i] * Wu0[(104 + i) * 128 + col];
      Pz[(hz * BN + b) * 128 + permc(col)] = s2;
    }
  } else {
    // ---- k_r: R = X@Wu0[0:40] + Z@Wu0[168:232] + bu0 ----
    __shared__ float xs[8][40];
    __shared__ float zs[8][64];
    const int r0 = (blk - 744) * 8;
    for (int idx = tid; idx < 320; idx += 256) xs[idx / 40][idx % 40] = X[r0 * 40 + idx];
    for (int idx = tid; idx < 512; idx += 256) {
      const int row = idx >> 6, c = idx & 63;
      zs[row][c] = Z[((r0 + row) / 20) * 64 + c];
    }
    __syncthreads();
    const int row = tid >> 5, cg = tid & 31;
    f32x4 acc = *reinterpret_cast<const f32x4*>(&bu[cg * 4]);
    #pragma unroll 4
    for (int k = 0; k < 40; ++k) {
      const float xv = xs[row][k];
      const f32x4 wv = *reinterpret_cast<const f32x4*>(&Wu0[k * 128 + cg * 4]);
      acc += xv * wv;
    }
    #pragma unroll 4
    for (int k = 0; k < 64; ++k) {
      const float zv = zs[row][k];
      const f32x4 wv = *reinterpret_cast<const f32x4*>(&Wu0[(168 + k) * 128 + cg * 4]);
      acc += zv * wv;
    }
    *reinterpret_cast<f32x4*>(&R[(r0 + row) * 128 + cg * 4]) = acc;
  }
}

// -------- eps(X) nets via MFMA, fused with Q = R + Xh@Wu0[40:104] ------------
// Q written as bf16 (perm cols).
__global__ __launch_bounds__(256) void k_xq(
    const float* __restrict__ X, const float* __restrict__ bx,
    const float* __restrict__ R,
    const unsigned short* __restrict__ WxP, const unsigned short* __restrict__ WuP,
    unsigned short* __restrict__ Qb)
{
  __shared__ __align__(16) unsigned char bufA[10240];  // [kk 2][nt 5][lane 64][16B]
  __shared__ __align__(16) unsigned char bufB[10240];
  const int hx = blockIdx.x >> 6;
  const int rt = blockIdx.x & 63;
  const int r0 = rt * 80;
  const int tid = threadIdx.x;
  const int w = tid >> 6, lane = tid & 63;
  const int l16 = lane & 15, lg = lane >> 4;
  const int lane16 = lane * 16;

  bf16x8 WA[5][2];
  #pragma unroll
  for (int l = 0; l < 5; ++l)
    #pragma unroll
    for (int kk = 0; kk < 2; ++kk)
      WA[l][kk] = *reinterpret_cast<const bf16x8*>(
          &WxP[(size_t)((((hx * 5 + l) * 2 + kk) * 4 + w) * 64 + lane) * 8]);
  bf16x8 WQ[2][2];
  #pragma unroll
  for (int kk = 0; kk < 2; ++kk)
    #pragma unroll
    for (int mt2 = 0; mt2 < 2; ++mt2)
      WQ[kk][mt2] = *reinterpret_cast<const bf16x8*>(
          &WuP[((kk * 8 + 2 * w + mt2) * 64 + lane) * 8]);

  for (int idx = tid; idx < 5120; idx += 256) {
    const int row = idx >> 6, k = idx & 63;
    const float v = (k < 40) ? X[(r0 + row) * 40 + k] : 0.f;
    const int kk = k >> 5, kl = k & 31;
    const int flg = (kl & 15) >> 2, fe = (kl & 3) + 4 * (kl >> 4);
    const int fl = (row & 15) + 16 * flg, nt = row >> 4;
    *reinterpret_cast<unsigned short*>(bufA + ((kk * 5 + nt) * 64 + fl) * 16 + fe * 2) = f2bf(v);
  }
  __syncthreads();

  const int kkp = w >> 1, half = w & 1;
  #pragma unroll
  for (int l = 0; l < 5; ++l) {
    const unsigned char* src = (l & 1) ? bufB : bufA;
    unsigned char* dst = (l & 1) ? bufA : bufB;
    const f32x4 bias = *reinterpret_cast<const f32x4*>(&bx[(l * 10 + hx) * 64 + w * 16 + 4 * lg]);
    #pragma unroll
    for (int nt = 0; nt < 5; ++nt) {
      const bf16x8 B0 = *reinterpret_cast<const bf16x8*>(src + nt * 1024 + lane16);
      const bf16x8 B1 = *reinterpret_cast<const bf16x8*>(src + (5 + nt) * 1024 + lane16);
      f32x4 acc = bias;
      acc = __builtin_amdgcn_mfma_f32_16x16x32_bf16(WA[l][0], B0, acc, 0, 0, 0);
      acc = __builtin_amdgcn_mfma_f32_16x16x32_bf16(WA[l][1], B1, acc, 0, 0, 0);
      u32x2 o;
      o[0] = cvt_pk(elu(acc[0]), elu(acc[1]));
      o[1] = cvt_pk(elu(acc[2]), elu(acc[3]));
      *reinterpret_cast<u32x2*>(dst + (kkp * 5 + nt) * 1024 + lane16 + half * 8) = o;
    }
    __syncthreads();
  }

  #pragma unroll
  for (int nt = 0; nt < 5; ++nt) {
    const bf16x8 B0 = *reinterpret_cast<const bf16x8*>(bufB + nt * 1024 + lane16);
    const bf16x8 B1 = *reinterpret_cast<const bf16x8*>(bufB + (5 + nt) * 1024 + lane16);
    const int grow = r0 + nt * 16 + l16;
    #pragma unroll
    for (int mt2 = 0; mt2 < 2; ++mt2) {
      f32x4 acc = *reinterpret_cast<const f32x4*>(&R[grow * 128 + (2 * w + mt2) * 16 + 4 * lg]);
      acc = __builtin_amdgcn_mfma_f32_16x16x32_bf16(WQ[0][mt2], B0, acc, 0, 0, 0);
      acc = __builtin_amdgcn_mfma_f32_16x16x32_bf16(WQ[1][mt2], B1, acc, 0, 0, 0);
      us4 o;
      #pragma unroll
      for (int r = 0; r < 4; ++r) {
        __bf16 h = (__bf16)acc[r];
        o[r] = __builtin_bit_cast(unsigned short, h);
      }
      *reinterpret_cast<us4*>(&Qb[(size_t)hx * 655360 + grow * 128 + w * 32 + lg * 8 + 4 * mt2]) = o;
    }
  }
}

// ---------------- fused 4x[128x128] MLP + logits + softmax ----------------
// FINAL config = R15 (best measured: k_fused ~137us, total 169us).
// 8 waves x 16 cols, grid 512 (2 blocks/CU — measured optimum; 640/768 all
// regress regardless of VGPR/LDS budgets), bf16 Q staging, lane16 layout
// (4.1M conflict cycles accepted: hidden by 4 waves/SIMD; the conflict-free
// layout regressed 25% via codegen pathology — R14).
__global__ __launch_bounds__(512, 4) void k_fused(
    const unsigned short* __restrict__ Qb, const float* __restrict__ Pz,
    const float* __restrict__ WuR, const float* __restrict__ bu,
    const float* __restrict__ Wlast, float* __restrict__ partial)
{
  __shared__ __align__(16) unsigned char frag[2][20480]; // [kk][nt][lane][16B]
  __shared__ float lgpS[640];                            // [wave 8][80 rows]

  const int tid  = threadIdx.x;
  const int w    = tid >> 6;           // 0..7
  const int lane = tid & 63;
  const int l16  = lane & 15;
  const int lg   = lane >> 4;
  const int lane16 = lane * 16;
  const int kkw  = w >> 1, half = w & 1;

  // ---- per-wave weight A-fragments, cols [16w,16w+16), all 4 layers ----
  bf16x8 wfrag[4][4];
  #pragma unroll
  for (int l = 0; l < 4; ++l)
    #pragma unroll
    for (int kk = 0; kk < 4; ++kk) {
      us8 wv;
      #pragma unroll
      for (int e = 0; e < 8; ++e) {
        const int k = kk * 32 + ((e < 4) ? (4 * lg + e) : (16 + 4 * lg + (e - 4)));
        const int out = w * 16 + l16;
        wv[e] = f2bf(WuR[l * 16384 + k * 128 + out]);
      }
      wfrag[l][kk] = __builtin_bit_cast(bf16x8, wv);
    }

  // Wlast fragment for this wave's 16 cols
  const f32x4 wl0 = *reinterpret_cast<const f32x4*>(&Wlast[w * 16 + 4 * lg]);

  // tile-invariant per-lane offsets (wave stages perm cols kkw*32+lg*8+4*half..+4)
  int qoff[5], pzoff[5];
  #pragma unroll
  for (int nt = 0; nt < 5; ++nt) {
    const int rloc = nt * 16 + l16;
    qoff[nt]  = rloc * 128 + kkw * 32 + lg * 8 + half * 4;        // ushort units
    pzoff[nt] = (rloc / 20) * 128 + kkw * 32 + lg * 8 + half * 4; // float units
  }

  for (int tile = blockIdx.x; tile < NTILES; tile += gridDim.x) {
    const int H  = tile >> 6;
    const int tb = tile & 63;
    const int hx = H / HZN, hz = H % HZN;
    const unsigned short* qp = Qb + (size_t)hx * 655360 + tb * (80 * 128);
    const float* pzt = Pz + (hz * BN + tb * 4) * 128;

    // ---- stage u1 = elu(Q + Pz): wave w fills its half-slice (8B/lane/nt) ----
    #pragma unroll
    for (int nt = 0; nt < 5; ++nt) {
      const bf16x4 q4 = *reinterpret_cast<const bf16x4*>(qp + qoff[nt]);
      const f32x4 pz = *reinterpret_cast<const f32x4*>(pzt + pzoff[nt]);
      bf16x4 o;
      #pragma unroll
      for (int e = 0; e < 4; ++e) o[e] = (__bf16)elu((float)q4[e] + pz[e]);
      *reinterpret_cast<bf16x4*>(frag[0] + (kkw * 5 + nt) * 1024 + lane16 + half * 8) = o;
    }
    __syncthreads();

    // ---- 4 hidden layers ----
    #pragma unroll
    for (int l = 0; l < 4; ++l) {
      const unsigned char* rdb = frag[l & 1];
      unsigned char* wrb = frag[(l & 1) ^ 1];
      const f32x4 bia = *reinterpret_cast<const f32x4*>(&bu[(l + 1) * 128 + w * 16 + 4 * lg]);
      #pragma unroll
      for (int nt = 0; nt < 5; ++nt) {
        f32x4 a0 = bia;
        #pragma unroll
        for (int kk = 0; kk < 4; ++kk) {
          const bf16x8 bfr = *reinterpret_cast<const bf16x8*>(rdb + (kk * 5 + nt) * 1024 + lane16);
          a0 = __builtin_amdgcn_mfma_f32_16x16x32_bf16(wfrag[l][kk], bfr, a0, 0, 0, 0);
        }
        if (l < 3) {
          bf16x4 o;
          #pragma unroll
          for (int r = 0; r < 4; ++r) o[r] = (__bf16)elu(a0[r]);
          *reinterpret_cast<bf16x4*>(wrb + (kkw * 5 + nt) * 1024 + lane16 + half * 8) = o;
        } else {
          float ps = 0.f;
          #pragma unroll
          for (int r = 0; r < 4; ++r) ps += elu(a0[r]) * wl0[r];
          ps += __shfl_xor(ps, 16);
          ps += __shfl_xor(ps, 32);
          if (lane < 16) lgpS[w * 80 + nt * 16 + l16] = ps;
        }
      }
      __syncthreads();
    }

    // ---- softmax: waves 0..3 handle b-group w (20 rows) ----
    if (w < 4) {
      const int a = lane;
      const int ar = (a < 20) ? a : 0;
      const int row = w * 20 + ar;
      float v = 0.f;
      #pragma unroll
      for (int j = 0; j < 8; ++j) v += lgpS[j * 80 + row];
      float m = (a < 20) ? v : -3.4e38f;
      #pragma unroll
      for (int off = 1; off <= 16; off <<= 1) m = fmaxf(m, __shfl_xor(m, off));
      float e = (a < 20) ? __expf(v - m) : 0.f;
      float s = e;
      #pragma unroll
      for (int off = 1; off <= 16; off <<= 1) s += __shfl_xor(s, off);
      float p = e / s;
      p = (p + 1e-6f) * (1.f / (1.f + 20.f * 1e-6f));
      if (a < 20) partial[(size_t)H * 5120 + tb * 80 + row] = p;
    }
    // frag[0] last read at l=2 (2 barriers before next staging); lgpS written
    // at l=3 pre-barrier, read by softmax post-barrier, rewritten 4 barriers
    // later. Safe without an extra barrier (same argument as R9/R12).
  }
}

// ---------------- mean over the 100 (hx,hz) samples ----------------
__global__ void k_reduce(const float* __restrict__ partial, float* __restrict__ out)
{
  const int i = blockIdx.x * 256 + threadIdx.x;
  if (i < 5120) {
    float s = 0.f;
    for (int h = 0; h < 100; ++h) s += partial[(size_t)h * 5120 + i];
    out[i] = s * 0.01f;
  }
}

extern "C" void kernel_launch(void* const* d_in, const int* in_sizes, int n_in,
                              void* d_out, int out_size, void* d_ws, size_t ws_size,
                              hipStream_t stream)
{
  const float* X     = (const float*)d_in[0];
  const float* Z     = (const float*)d_in[1];
  const float* Wx0   = (const float*)d_in[2];
  const float* WxR   = (const float*)d_in[3];
  const float* bx    = (const float*)d_in[4];
  const float* Wz0   = (const float*)d_in[5];
  const float* WzR   = (const float*)d_in[6];
  const float* bz    = (const float*)d_in[7];
  const float* Wu0   = (const float*)d_in[8];
  const float* WuR   = (const float*)d_in[9];
  const float* bu    = (const float*)d_in[10];
  const float* Wlast = (const float*)d_in[11];
  float* out = (float*)d_out;

  float* ws      = (float*)d_ws;
  float* Pz      = ws;                          // 327,680 f32
  float* Rb      = Pz + 327680;                 // 655,360 f32
  unsigned short* Qb = (unsigned short*)(Rb + 655360);  // 6,553,600 us
  float* partial = (float*)(Qb + 6553600);      // 512,000 f32
  unsigned short* WxP = (unsigned short*)(partial + 512000);  // 204,800 us
  unsigned short* WuP = WxP + 204800;           // 8,192 us

  hipLaunchKernelGGL(k_pre, dim3(1384), dim3(256), 0, stream,
                     X, Z, Wx0, WxR, Wz0, WzR, bz, Wu0, bu, WxP, WuP, Pz, Rb);
  hipLaunchKernelGGL(k_xq, dim3(640), dim3(256), 0, stream, X, bx, Rb, WxP, WuP, Qb);
  hipLaunchKernelGGL(k_fused, dim3(512), dim3(512), 0, stream, Qb, Pz, WuR, bu, Wlast, partial);
  hipLaunchKernelGGL(k_reduce, dim3(20), dim3(256), 0, stream, partial, out);
}